// Round 9
// baseline (189.148 us; speedup 1.0000x reference)
//
#include <hip/hip_runtime.h>

typedef unsigned short u16;
typedef unsigned int   u32;
typedef __bf16 bfv8 __attribute__((ext_vector_type(8)));   // MFMA A/B frag: 8 bf16
typedef float  f32x4 __attribute__((ext_vector_type(4)));  // MFMA C/D frag
typedef short  s16x4 __attribute__((ext_vector_type(4)));  // 16x16x16 bf16_1k frag

#define B_   2
#define T_   2048
#define D_   1024
#define H_   16
#define HKV_ 4
#define NQK  1280            // qkv buffer holds Q(1024) + K(256); V goes to vT
#define BT_  (B_*T_)
// q_gain fold also includes 1/sqrt(64)=0.125 and log2(e) (softmax in log2 domain)
#define QSCALE 0.18033688011112042f
#define L2_10K 0.41524101186092515f   // log2(10000)/32
#define I2PI   0.15915494309189535f   // 1/(2*pi) — HW trig input is revolutions

__device__ __forceinline__ u16 f2bf(float f) {   // native RNE cvt
  __bf16 h = (__bf16)f; u16 s; __builtin_memcpy(&s, &h, 2); return s;
}

// async global->LDS, 16B per lane; LDS dst = wave-uniform base + lane*16 (m104)
__device__ __forceinline__ void load16(const u16* g, u16* l) {
  auto gp = (const __attribute__((address_space(1))) u32*)(uintptr_t)g;
  auto lp = (__attribute__((address_space(3))) u32*)(uintptr_t)l;
  __builtin_amdgcn_global_load_lds(gp, lp, 16, 0, 0);
}

// HW trig: v_sin_f32/v_cos_f32 take revolutions; explicit fract reduction
__device__ __forceinline__ void hw_sincos_rev(float rev, float& s, float& c) {
  rev -= floorf(rev);                  // folds to v_fract_f32
  s = __builtin_amdgcn_sinf(rev);
  c = __builtin_amdgcn_cosf(rev);
}

// ---------------- fp32 -> bf16 convert: x AND all weights in ONE launch ----------
// dst is contiguous: xb(4194304) | Wq(1048576) | Wk(262144) | Wv(262144) | Wp(1048576)
__global__ void conv_all_kernel(const float* __restrict__ x,
                                const float* __restrict__ wq, const float* __restrict__ wk,
                                const float* __restrict__ wv, const float* __restrict__ wp,
                                u16* __restrict__ dst) {
  int i = (blockIdx.x * 256 + threadIdx.x) * 4;
  const float* s; int off;
  if (i < 4194304) { s = x; off = i; }
  else {
    int j = i - 4194304;
    if      (j < 1048576) { s = wq; off = j; }
    else if (j < 1310720) { s = wk; off = j - 1048576; }
    else if (j < 1572864) { s = wv; off = j - 1310720; }
    else                  { s = wp; off = j - 1572864; }
  }
  float4 v = *(const float4*)(s + off);
  ushort4 o; o.x = f2bf(v.x); o.y = f2bf(v.y); o.z = f2bf(v.z); o.w = f2bf(v.w);
  *(ushort4*)(dst + i) = o;
}

// ---------------- bf16 GEMM, C = A(M,K) @ B(N,K)^T, m97-style ----------------
// MODE 0: f32 out ld=N.
// MODE 2: fused QKV epilogue — Q/K cols get RoPE (+q_gain*QSCALE on Q) applied
//         on fp32 accumulators (HW v_sin/v_cos, NOT libm sincosf — scratch!);
//         V cols scattered transposed to vT[b][kvh][d][t].
template<int MODE>
__global__ __launch_bounds__(256) void gemm_bt(const u16* __restrict__ A,
                                               const u16* __restrict__ Bm,
                                               void* __restrict__ C,
                                               u16* __restrict__ vT,
                                               const float* __restrict__ qg,
                                               int M, int N, int K) {
  __shared__ __align__(16) u16 As[128 * 32];
  __shared__ __align__(16) u16 Bs[128 * 32];
  const int tid  = threadIdx.x;
  const int wave = tid >> 6, lane = tid & 63;
  const int quad = lane >> 4, l16 = lane & 15;
  const int m0 = blockIdx.y * 128, n0 = blockIdx.x * 128;
  const int wm = (wave >> 1) * 64, wn = (wave & 1) * 64;
  const int lr = lane >> 2, lc = (lane & 3) * 8;

  f32x4 acc[4][4];
  for (int mi = 0; mi < 4; ++mi)
    for (int ni = 0; ni < 4; ++ni) acc[mi][ni] = (f32x4){0.f, 0.f, 0.f, 0.f};

  for (int kk = 0; kk < K; kk += 32) {
    __syncthreads();
    #pragma unroll
    for (int u = 0; u < 2; ++u) {
      const int c = wave * 2 + u;
      const int r = c * 16 + lr;
      load16(A  + (size_t)(m0 + r) * K + kk + lc, As + c * 512);
      load16(Bm + (size_t)(n0 + r) * K + kk + lc, Bs + c * 512);
    }
    __syncthreads();
    bfv8 af[4], bf_[4];
    #pragma unroll
    for (int i = 0; i < 4; ++i) af[i]  = *(const bfv8*)(As + (wm + i*16 + l16)*32 + 8*quad);
    #pragma unroll
    for (int i = 0; i < 4; ++i) bf_[i] = *(const bfv8*)(Bs + (wn + i*16 + l16)*32 + 8*quad);
    #pragma unroll
    for (int mi = 0; mi < 4; ++mi)
      #pragma unroll
      for (int ni = 0; ni < 4; ++ni)
        acc[mi][ni] = __builtin_amdgcn_mfma_f32_16x16x32_bf16(af[mi], bf_[ni], acc[mi][ni], 0, 0, 0);
  }

  // C/D layout: row = 4*quad + reg, col = l16 (+16*ni +wn +n0)
  if (MODE == 0) {
    #pragma unroll
    for (int mi = 0; mi < 4; ++mi)
      #pragma unroll
      for (int ni = 0; ni < 4; ++ni)
        #pragma unroll
        for (int r = 0; r < 4; ++r)
          ((float*)C)[(size_t)(m0 + wm + mi*16 + 4*quad + r) * N + n0 + wn + ni*16 + l16]
            = acc[mi][ni][r];
  } else {
    const int colbase = n0 + wn;                 // 64-aligned => exactly one head
    if (colbase < NQK) {                         // Q or K head: apply RoPE here
      const bool isQ = colbase < 1024;
      const float gain = isQ ? qg[colbase >> 6] * QSCALE : 1.0f;
      // lane's head-internal cols: j0=l16 (ni 0/2 pair), j1=l16+16 (ni 1/3 pair)
      const float inv0 = exp2f(-(float)l16 * L2_10K) * I2PI;          // rev/step
      const float inv1 = exp2f(-(float)(l16 + 16) * L2_10K) * I2PI;
      #pragma unroll
      for (int mi = 0; mi < 4; ++mi) {
        const int rowg = m0 + wm + mi*16 + 4*quad;
        u16* dst = (u16*)C + (size_t)rowg * NQK + colbase + l16;
        #pragma unroll
        for (int r = 0; r < 4; ++r) {
          const int t = (rowg + r) & (T_ - 1);
          float s0, c0, s1, c1;
          hw_sincos_rev((float)t * inv0, s0, c0);
          hw_sincos_rev((float)t * inv1, s1, c1);
          const float x1a = acc[mi][0][r], x2a = acc[mi][2][r];
          const float x1b = acc[mi][1][r], x2b = acc[mi][3][r];
          u16* drow = dst + (size_t)r * NQK;
          drow[0]  = f2bf((x1a*c0 - x2a*s0) * gain);
          drow[16] = f2bf((x1b*c1 - x2b*s1) * gain);
          drow[32] = f2bf((x1a*s0 + x2a*c0) * gain);
          drow[48] = f2bf((x1b*s1 + x2b*c1) * gain);
        }
      }
    } else {              // V region -> transposed vT[b][kvh][d][t]
      #pragma unroll
      for (int mi = 0; mi < 4; ++mi)
        #pragma unroll
        for (int ni = 0; ni < 4; ++ni) {
          const int dd  = colbase + ni*16 + l16 - NQK;
          const int kvh = dd >> 6, d = dd & 63;
          const int rowg = m0 + wm + mi*16 + 4*quad;
          const int bb = rowg >> 11, t = rowg & (T_ - 1);
          ushort4 w4;
          w4.x = f2bf(acc[mi][ni][0]); w4.y = f2bf(acc[mi][ni][1]);
          w4.z = f2bf(acc[mi][ni][2]); w4.w = f2bf(acc[mi][ni][3]);
          *(ushort4*)(vT + ((size_t)((bb*HKV_ + kvh)*64 + d)) * T_ + t) = w4;
        }
    }
  }
}

// ---------------- Flash attention (causal, GQA, S^T trick, UNPAIRED) ----------------
// Un-paired q-tiles: total stagings / LDS reads / MFMA are identical to the
// paired variant (verified arithmetic), but grid doubles to 1024 blocks ->
// 4-5 blocks/CU (vs 2) for latency hiding. Longest blocks scheduled first
// (qt = 31 - blockIdx.x) so the drain tail is short blocks.
// St = K Q^T (C-layout lane l16 = q-row, keys 4*quad+r) feeds P directly into
// PV (O^T = V^T P^T) as 16x16x16bf16_1k B-frags — no P LDS round-trip.
// Fixed-max softmax (M=0, log2 domain, scores O(1)-bounded).
template<bool DIAG>
__device__ __forceinline__ void attn_tile(const u16* KB, const u16* VB,
                                          int l16, int quad, const bfv8* q,
                                          float& ps, f32x4 oacc[4],
                                          int qCol, int s0) {
  const int sw = l16 & 7;
  f32x4 st[4];
  #pragma unroll
  for (int ni = 0; ni < 4; ++ni) {
    const int row = ni*16 + l16;           // key row in K tile
    bfv8 k0 = *(const bfv8*)(KB + row*64 + 8*(quad ^ sw));
    bfv8 k1 = *(const bfv8*)(KB + row*64 + 8*((quad + 4) ^ sw));
    st[ni] = __builtin_amdgcn_mfma_f32_16x16x32_bf16(k0, q[0], (f32x4){0.f,0.f,0.f,0.f}, 0, 0, 0);
    st[ni] = __builtin_amdgcn_mfma_f32_16x16x32_bf16(k1, q[1], st[ni], 0, 0, 0);
  }
  // mask + exp2 + per-lane row-sum + pack to bf16 B-frags (P^T in registers)
  s16x4 pb[4];
  #pragma unroll
  for (int ni = 0; ni < 4; ++ni)
    #pragma unroll
    for (int r = 0; r < 4; ++r) {
      float v = st[ni][r];
      if (DIAG) {
        const int key = s0 + ni*16 + 4*quad + r;
        v = (key <= qCol) ? v : -3.0e38f;
      }
      const float p = __builtin_amdgcn_exp2f(v);
      ps += p;
      pb[ni][r] = (short)f2bf(p);
    }
  // O^T += V^T P^T
  #pragma unroll
  for (int ni = 0; ni < 4; ++ni) {
    const int vofs = 8*((2*ni + (quad >> 1)) ^ sw) + 4*(quad & 1);
    #pragma unroll
    for (int dt = 0; dt < 4; ++dt) {
      s16x4 va = *(const s16x4*)(VB + (dt*16 + l16)*64 + vofs);
      oacc[dt] = __builtin_amdgcn_mfma_f32_16x16x16bf16_1k(va, pb[ni], oacc[dt], 0, 0, 0);
    }
  }
}

__global__ __launch_bounds__(256) void attn_kernel(const u16* __restrict__ qkv,
                                                   const u16* __restrict__ vT,
                                                   u16* __restrict__ o) {
  const int qt = 31 - blockIdx.x;       // longest-first scheduling
  const int h  = blockIdx.y;
  const int b  = blockIdx.z;
  const int kvh = h >> 2;
  const int tid = threadIdx.x;
  const int wave = tid >> 6, lane = tid & 63;
  const int quad = lane >> 4, l16 = lane & 15;
  const int nk  = qt + 1;

  __shared__ __align__(16) u16 Kl[2][64 * 64];
  __shared__ __align__(16) u16 Vl[2][64 * 64];

  const u16* qp = qkv + (size_t)(b*T_ + qt*64 + wave*16 + l16) * NQK + h*64 + 8*quad;
  const bfv8 q[2] = { *(const bfv8*)qp, *(const bfv8*)(qp + 32) };

  float ps = 0.f;
  f32x4 oacc[4];
  #pragma unroll
  for (int d = 0; d < 4; ++d) oacc[d] = (f32x4){0.f, 0.f, 0.f, 0.f};

  const int srow = lane >> 3, slot = lane & 7;
  const u16* Kg = qkv + (size_t)(b*T_) * NQK + 1024 + kvh*64;
  const u16* Vg = vT  + (size_t)((b*HKV_ + kvh) * 64) * T_;

  auto stage = [&](int kt, int buf) {
    const int s0 = kt * 64;
    #pragma unroll
    for (int u = 0; u < 2; ++u) {
      const int base = wave*16 + u*8;
      const int r  = base + srow;
      const int kc = slot ^ (r & 7);           // XOR chunk swizzle
      load16(Kg + (size_t)(s0 + r) * NQK + kc*8, Kl[buf] + base*64);
      load16(Vg + (size_t)r * T_ + s0 + kc*8,    Vl[buf] + base*64);
    }
  };

  stage(0, 0);
  const int qCol = qt*64 + wave*16 + l16;      // lane's q row

  for (int kt = 0; kt < nk - 1; ++kt) {
    __syncthreads();                           // drains DMA(kt)
    stage(kt + 1, (kt + 1) & 1);
    attn_tile<false>(Kl[kt & 1], Vl[kt & 1], l16, quad, q, ps, oacc, qCol, kt*64);
  }
  {
    const int kt = nk - 1;
    __syncthreads();
    attn_tile<true>(Kl[kt & 1], Vl[kt & 1], l16, quad, q, ps, oacc, qCol, kt*64);
  }

  // row sum: partials live on the 4 quads of each q-row lane
  #pragma unroll
  for (int off = 16; off < 64; off <<= 1) ps += __shfl_xor(ps, off);
  const float iv = 1.0f / ps;

  // O^T C-layout: col=l16=qrow, row=4*quad+r = d (+16*dt) -> pack 4 d's per store
  #pragma unroll
  for (int dt = 0; dt < 4; ++dt) {
    ushort4 w;
    w.x = f2bf(oacc[dt][0]*iv); w.y = f2bf(oacc[dt][1]*iv);
    w.z = f2bf(oacc[dt][2]*iv); w.w = f2bf(oacc[dt][3]*iv);
    *(ushort4*)(o + (size_t)(b*T_ + qCol) * D_ + h*64 + dt*16 + 4*quad) = w;
  }
}

// ---------------- launch ----------------
extern "C" void kernel_launch(void* const* d_in, const int* in_sizes, int n_in,
                              void* d_out, int out_size, void* d_ws, size_t ws_size,
                              hipStream_t stream) {
  const float* x  = (const float*)d_in[0];
  const float* Wq = (const float*)d_in[1];
  const float* Wk = (const float*)d_in[2];
  const float* Wv = (const float*)d_in[3];
  const float* Wp = (const float*)d_in[4];
  const float* qg = (const float*)d_in[5];

  u16* xb   = (u16*)d_ws;                        // 4096 x 1024 (reused as ob)
  u16* wqkv = xb   + (size_t)BT_ * D_;           // 1536 x 1024
  u16* wpb  = wqkv + (size_t)1536 * D_;          // 1024 x 1024 (contiguous after wqkv)
  u16* qkvb = wpb  + (size_t)D_ * D_;            // 4096 x 1280 (Q|K)
  u16* vT   = qkvb + (size_t)BT_ * NQK;          // [2][4][64][2048]
  u16* ob   = xb;

  conv_all_kernel<<<dim3((4194304 + 2621440) / 1024), dim3(256), 0, stream>>>(
      x, Wq, Wk, Wv, Wp, xb);

  gemm_bt<2><<<dim3(12, 32), dim3(256), 0, stream>>>(xb, wqkv, qkvb, vT, qg, BT_, 1536, D_);
  attn_kernel<<<dim3(32, H_, B_), dim3(256), 0, stream>>>(qkvb, vT, ob);
  gemm_bt<0><<<dim3(8, 32), dim3(256), 0, stream>>>(ob, wpb, d_out, (u16*)nullptr, nullptr, BT_, D_, D_);
}

// Round 10
// 174.321 us; speedup vs baseline: 1.0851x; 1.0851x over previous
//
#include <hip/hip_runtime.h>

typedef unsigned short u16;
typedef unsigned int   u32;
typedef __bf16 bfv8 __attribute__((ext_vector_type(8)));   // MFMA A/B frag: 8 bf16
typedef float  f32x4 __attribute__((ext_vector_type(4)));  // MFMA C/D frag
typedef short  s16x4 __attribute__((ext_vector_type(4)));  // 16x16x16 bf16_1k frag

#define B_   2
#define T_   2048
#define D_   1024
#define H_   16
#define HKV_ 4
#define NQK  1280            // qkv buffer holds Q(1024) + K(256); V goes to vT
#define BT_  (B_*T_)
// q_gain fold also includes 1/sqrt(64)=0.125 and log2(e) (softmax in log2 domain)
#define QSCALE 0.18033688011112042f
#define L2_10K 0.41524101186092515f   // log2(10000)/32
#define I2PI   0.15915494309189535f   // 1/(2*pi) — HW trig input is revolutions

__device__ __forceinline__ u16 f2bf(float f) {   // native RNE cvt
  __bf16 h = (__bf16)f; u16 s; __builtin_memcpy(&s, &h, 2); return s;
}

// async global->LDS, 16B per lane; LDS dst = wave-uniform base + lane*16 (m104)
__device__ __forceinline__ void load16(const u16* g, u16* l) {
  auto gp = (const __attribute__((address_space(1))) u32*)(uintptr_t)g;
  auto lp = (__attribute__((address_space(3))) u32*)(uintptr_t)l;
  __builtin_amdgcn_global_load_lds(gp, lp, 16, 0, 0);
}

// HW trig: v_sin_f32/v_cos_f32 take revolutions; explicit fract reduction
__device__ __forceinline__ void hw_sincos_rev(float rev, float& s, float& c) {
  rev -= floorf(rev);                  // folds to v_fract_f32
  s = __builtin_amdgcn_sinf(rev);
  c = __builtin_amdgcn_cosf(rev);
}

// ---------------- fp32 -> bf16 convert: x AND all weights in ONE launch ----------
// dst is contiguous: xb(4194304) | Wq(1048576) | Wk(262144) | Wv(262144) | Wp(1048576)
__global__ void conv_all_kernel(const float* __restrict__ x,
                                const float* __restrict__ wq, const float* __restrict__ wk,
                                const float* __restrict__ wv, const float* __restrict__ wp,
                                u16* __restrict__ dst) {
  int i = (blockIdx.x * 256 + threadIdx.x) * 4;
  const float* s; int off;
  if (i < 4194304) { s = x; off = i; }
  else {
    int j = i - 4194304;
    if      (j < 1048576) { s = wq; off = j; }
    else if (j < 1310720) { s = wk; off = j - 1048576; }
    else if (j < 1572864) { s = wv; off = j - 1310720; }
    else                  { s = wp; off = j - 1572864; }
  }
  float4 v = *(const float4*)(s + off);
  ushort4 o; o.x = f2bf(v.x); o.y = f2bf(v.y); o.z = f2bf(v.z); o.w = f2bf(v.w);
  *(ushort4*)(dst + i) = o;
}

// ---------------- bf16 GEMM, C = A(M,K) @ B(N,K)^T ----------------
// 2-wave blocks (128 thr), tile 128(M) x 64(N), BK=32; each wave owns a full
// 64x64 (4x4 mfma tiles) -> MFMA:LDS-read ratio 2.0 (same as 128^2/4-wave),
// but 2x the block count for grid occupancy (gemm1 768, gemm2 512 blocks).
// MODE 0: f32 out ld=N.
// MODE 2: fused QKV epilogue — block's 64-col range = exactly one head.
//         Q/K heads get RoPE (+q_gain*QSCALE on Q) on fp32 accumulators
//         (HW v_sin/v_cos, NOT libm sincosf — scratch!); V heads scattered
//         transposed to vT[b][kvh][d][t].
template<int MODE>
__global__ __launch_bounds__(128) void gemm_bt(const u16* __restrict__ A,
                                               const u16* __restrict__ Bm,
                                               void* __restrict__ C,
                                               u16* __restrict__ vT,
                                               const float* __restrict__ qg,
                                               int M, int N, int K) {
  __shared__ __align__(16) u16 As[128 * 32];   // 8 KB
  __shared__ __align__(16) u16 Bs[64 * 32];    // 4 KB
  const int tid  = threadIdx.x;
  const int wave = tid >> 6, lane = tid & 63;
  const int quad = lane >> 4, l16 = lane & 15;
  const int m0 = blockIdx.y * 128, n0 = blockIdx.x * 64;
  const int wm = wave * 64;
  const int lr = lane >> 2, lc = (lane & 3) * 8;   // 4 lanes per 32-half row

  f32x4 acc[4][4];
  for (int mi = 0; mi < 4; ++mi)
    for (int ni = 0; ni < 4; ++ni) acc[mi][ni] = (f32x4){0.f, 0.f, 0.f, 0.f};

  for (int kk = 0; kk < K; kk += 32) {
    __syncthreads();
    #pragma unroll
    for (int u = 0; u < 4; ++u) {            // A: 8 chunks of 16 rows
      const int c = u * 2 + wave;            // wave-uniform chunk id
      load16(A + (size_t)(m0 + c*16 + lr) * K + kk + lc, As + c * 512);
    }
    #pragma unroll
    for (int u = 0; u < 2; ++u) {            // B: 4 chunks of 16 rows
      const int c = u * 2 + wave;
      load16(Bm + (size_t)(n0 + c*16 + lr) * K + kk + lc, Bs + c * 512);
    }
    __syncthreads();                         // implicit vmcnt(0): DMA done
    bfv8 af[4], bf_[4];
    #pragma unroll
    for (int i = 0; i < 4; ++i) af[i]  = *(const bfv8*)(As + (wm + i*16 + l16)*32 + 8*quad);
    #pragma unroll
    for (int i = 0; i < 4; ++i) bf_[i] = *(const bfv8*)(Bs + (i*16 + l16)*32 + 8*quad);
    #pragma unroll
    for (int mi = 0; mi < 4; ++mi)
      #pragma unroll
      for (int ni = 0; ni < 4; ++ni)
        acc[mi][ni] = __builtin_amdgcn_mfma_f32_16x16x32_bf16(af[mi], bf_[ni], acc[mi][ni], 0, 0, 0);
  }

  // C/D layout: row = 4*quad + reg, col = l16 (+16*ni +n0)
  if (MODE == 0) {
    #pragma unroll
    for (int mi = 0; mi < 4; ++mi)
      #pragma unroll
      for (int ni = 0; ni < 4; ++ni)
        #pragma unroll
        for (int r = 0; r < 4; ++r)
          ((float*)C)[(size_t)(m0 + wm + mi*16 + 4*quad + r) * N + n0 + ni*16 + l16]
            = acc[mi][ni][r];
  } else {
    if (n0 < NQK) {                          // Q or K head: apply RoPE here
      const bool isQ = n0 < 1024;
      const float gain = isQ ? qg[n0 >> 6] * QSCALE : 1.0f;
      // lane's head-internal cols: j0=l16 (ni 0/2 pair), j1=l16+16 (ni 1/3 pair)
      const float inv0 = exp2f(-(float)l16 * L2_10K) * I2PI;          // rev/step
      const float inv1 = exp2f(-(float)(l16 + 16) * L2_10K) * I2PI;
      #pragma unroll
      for (int mi = 0; mi < 4; ++mi) {
        const int rowg = m0 + wm + mi*16 + 4*quad;
        u16* dst = (u16*)C + (size_t)rowg * NQK + n0 + l16;
        #pragma unroll
        for (int r = 0; r < 4; ++r) {
          const int t = (rowg + r) & (T_ - 1);
          float s0, c0, s1, c1;
          hw_sincos_rev((float)t * inv0, s0, c0);
          hw_sincos_rev((float)t * inv1, s1, c1);
          const float x1a = acc[mi][0][r], x2a = acc[mi][2][r];
          const float x1b = acc[mi][1][r], x2b = acc[mi][3][r];
          u16* drow = dst + (size_t)r * NQK;
          drow[0]  = f2bf((x1a*c0 - x2a*s0) * gain);
          drow[16] = f2bf((x1b*c1 - x2b*s1) * gain);
          drow[32] = f2bf((x1a*s0 + x2a*c0) * gain);
          drow[48] = f2bf((x1b*s1 + x2b*c1) * gain);
        }
      }
    } else {              // V head -> transposed vT[b][kvh][d][t]
      const int kvh = (n0 - NQK) >> 6;
      #pragma unroll
      for (int mi = 0; mi < 4; ++mi)
        #pragma unroll
        for (int ni = 0; ni < 4; ++ni) {
          const int d = ni*16 + l16;
          const int rowg = m0 + wm + mi*16 + 4*quad;
          const int bb = rowg >> 11, t = rowg & (T_ - 1);
          ushort4 w4;
          w4.x = f2bf(acc[mi][ni][0]); w4.y = f2bf(acc[mi][ni][1]);
          w4.z = f2bf(acc[mi][ni][2]); w4.w = f2bf(acc[mi][ni][3]);
          *(ushort4*)(vT + ((size_t)((bb*HKV_ + kvh)*64 + d)) * T_ + t) = w4;
        }
    }
  }
}

// ---------------- Flash attention (causal, GQA, paired q-tiles, S^T trick) ----------------
// R8 version (best measured: 45.6 us). Paired q-tiles (i, 31-i): uniform 33
// strip-tiles/block AND K/V frag reads shared across both strips (R9 lesson:
// unpairing costs +35% staging & frag reads — pairing is strictly better).
// St = K Q^T (C-layout lane l16 = q-row, keys 4*quad+r) feeds P directly into
// PV (O^T = V^T P^T) as 16x16x16bf16_1k B-frags — no P LDS round-trip.
// Fixed-max softmax (M=0, log2 domain, scores O(1)-bounded).
// COMPILE-TIME strip/diag specialization (R7 lesson: runtime bools get
// if-converted inside unrolled loops -> dead strip's exp2/MFMA chain executes).
template<bool DOA, bool DIAGA, bool DIAGB>
__device__ __forceinline__ void attn_tile(const u16* KB, const u16* VB,
                                          int l16, int quad,
                                          const bfv8* qA, const bfv8* qB,
                                          float& psA, float& psB,
                                          f32x4 oA[4], f32x4 oB[4],
                                          int qColA, int qColB, int s0) {
  const int sw = l16 & 7;
  f32x4 stA[4], stB[4];
  #pragma unroll
  for (int ni = 0; ni < 4; ++ni) {
    const int row = ni*16 + l16;           // key row in K tile
    bfv8 k0 = *(const bfv8*)(KB + row*64 + 8*(quad ^ sw));
    bfv8 k1 = *(const bfv8*)(KB + row*64 + 8*((quad + 4) ^ sw));
    if (DOA) {
      stA[ni] = __builtin_amdgcn_mfma_f32_16x16x32_bf16(k0, qA[0], (f32x4){0.f,0.f,0.f,0.f}, 0, 0, 0);
      stA[ni] = __builtin_amdgcn_mfma_f32_16x16x32_bf16(k1, qA[1], stA[ni], 0, 0, 0);
    }
    stB[ni] = __builtin_amdgcn_mfma_f32_16x16x32_bf16(k0, qB[0], (f32x4){0.f,0.f,0.f,0.f}, 0, 0, 0);
    stB[ni] = __builtin_amdgcn_mfma_f32_16x16x32_bf16(k1, qB[1], stB[ni], 0, 0, 0);
  }
  // mask + exp2 + per-lane row-sum + pack to bf16 B-frags (P^T in registers)
  s16x4 pbA[4], pbB[4];
  #pragma unroll
  for (int ni = 0; ni < 4; ++ni)
    #pragma unroll
    for (int r = 0; r < 4; ++r) {
      const int key = s0 + ni*16 + 4*quad + r;
      if (DOA) {
        float v = stA[ni][r];
        if (DIAGA) v = (key <= qColA) ? v : -3.0e38f;
        const float p = __builtin_amdgcn_exp2f(v);
        psA += p;
        pbA[ni][r] = (short)f2bf(p);
      }
      float v = stB[ni][r];
      if (DIAGB) v = (key <= qColB) ? v : -3.0e38f;
      const float p = __builtin_amdgcn_exp2f(v);
      psB += p;
      pbB[ni][r] = (short)f2bf(p);
    }
  // O^T += V^T P^T  (shared V frags)
  #pragma unroll
  for (int ni = 0; ni < 4; ++ni) {
    const int vofs = 8*((2*ni + (quad >> 1)) ^ sw) + 4*(quad & 1);
    #pragma unroll
    for (int dt = 0; dt < 4; ++dt) {
      s16x4 va = *(const s16x4*)(VB + (dt*16 + l16)*64 + vofs);
      if (DOA) oA[dt] = __builtin_amdgcn_mfma_f32_16x16x16bf16_1k(va, pbA[ni], oA[dt], 0, 0, 0);
      oB[dt] = __builtin_amdgcn_mfma_f32_16x16x16bf16_1k(va, pbB[ni], oB[dt], 0, 0, 0);
    }
  }
}

__global__ __launch_bounds__(256) void attn_kernel(const u16* __restrict__ qkv,
                                                   const u16* __restrict__ vT,
                                                   u16* __restrict__ o) {
  const int pr = blockIdx.x;            // pair id 0..15 -> q-tiles (pr, 31-pr)
  const int h  = blockIdx.y;
  const int b  = blockIdx.z;
  const int kvh = h >> 2;
  const int tid = threadIdx.x;
  const int wave = tid >> 6, lane = tid & 63;
  const int quad = lane >> 4, l16 = lane & 15;

  const int qtA = pr, qtB = 31 - pr;
  const int nk  = qtB + 1;              // qtA < qtB always (pr in 0..15)

  __shared__ __align__(16) u16 Kl[2][64 * 64];
  __shared__ __align__(16) u16 Vl[2][64 * 64];

  const u16* qAp = qkv + (size_t)(b*T_ + qtA*64 + wave*16 + l16) * NQK + h*64 + 8*quad;
  const u16* qBp = qkv + (size_t)(b*T_ + qtB*64 + wave*16 + l16) * NQK + h*64 + 8*quad;
  const bfv8 qA[2] = { *(const bfv8*)qAp, *(const bfv8*)(qAp + 32) };
  const bfv8 qB[2] = { *(const bfv8*)qBp, *(const bfv8*)(qBp + 32) };

  float psA = 0.f, psB = 0.f;
  f32x4 oA[4], oB[4];
  #pragma unroll
  for (int d = 0; d < 4; ++d) oA[d] = oB[d] = (f32x4){0.f, 0.f, 0.f, 0.f};

  const int srow = lane >> 3, slot = lane & 7;
  const u16* Kg = qkv + (size_t)(b*T_) * NQK + 1024 + kvh*64;
  const u16* Vg = vT  + (size_t)((b*HKV_ + kvh) * 64) * T_;

  auto stage = [&](int kt, int buf) {
    const int s0 = kt * 64;
    #pragma unroll
    for (int u = 0; u < 2; ++u) {
      const int base = wave*16 + u*8;
      const int r  = base + srow;
      const int kc = slot ^ (r & 7);           // XOR chunk swizzle
      load16(Kg + (size_t)(s0 + r) * NQK + kc*8, Kl[buf] + base*64);
      load16(Vg + (size_t)r * T_ + s0 + kc*8,    Vl[buf] + base*64);
    }
  };

  stage(0, 0);
  const int qColA = qtA*64 + wave*16 + l16;    // lane's q row (strip A)
  const int qColB = qtB*64 + wave*16 + l16;

  // Phase 1: kt in [0, qtA) — both strips, no diag
  for (int kt = 0; kt < qtA; ++kt) {
    __syncthreads();
    stage(kt + 1, (kt + 1) & 1);
    attn_tile<true, false, false>(Kl[kt & 1], Vl[kt & 1], l16, quad, qA, qB,
                                  psA, psB, oA, oB, qColA, qColB, kt*64);
  }
  // kt = qtA — both strips, diag on A (qtA < nk-1 always)
  {
    const int kt = qtA;
    __syncthreads();
    stage(kt + 1, (kt + 1) & 1);
    attn_tile<true, true, false>(Kl[kt & 1], Vl[kt & 1], l16, quad, qA, qB,
                                 psA, psB, oA, oB, qColA, qColB, kt*64);
  }
  // Phase 2: kt in (qtA, nk-1) — strip B only
  for (int kt = qtA + 1; kt < nk - 1; ++kt) {
    __syncthreads();
    stage(kt + 1, (kt + 1) & 1);
    attn_tile<false, false, false>(Kl[kt & 1], Vl[kt & 1], l16, quad, qA, qB,
                                   psA, psB, oA, oB, qColA, qColB, kt*64);
  }
  // kt = nk-1 — strip B, diag
  {
    const int kt = nk - 1;
    __syncthreads();
    attn_tile<false, false, true>(Kl[kt & 1], Vl[kt & 1], l16, quad, qA, qB,
                                  psA, psB, oA, oB, qColA, qColB, kt*64);
  }

  // row sums: partials live on the 4 quads of each q-row lane
  #pragma unroll
  for (int off = 16; off < 64; off <<= 1) {
    psA += __shfl_xor(psA, off);
    psB += __shfl_xor(psB, off);
  }
  const float ivA = 1.0f / psA, ivB = 1.0f / psB;

  // O^T C-layout: col=l16=qrow, row=4*quad+r = d (+16*dt) -> pack 4 d's per store
  #pragma unroll
  for (int dt = 0; dt < 4; ++dt) {
    ushort4 wA, wB;
    wA.x = f2bf(oA[dt][0]*ivA); wA.y = f2bf(oA[dt][1]*ivA);
    wA.z = f2bf(oA[dt][2]*ivA); wA.w = f2bf(oA[dt][3]*ivA);
    wB.x = f2bf(oB[dt][0]*ivB); wB.y = f2bf(oB[dt][1]*ivB);
    wB.z = f2bf(oB[dt][2]*ivB); wB.w = f2bf(oB[dt][3]*ivB);
    *(ushort4*)(o + (size_t)(b*T_ + qColA) * D_ + h*64 + dt*16 + 4*quad) = wA;
    *(ushort4*)(o + (size_t)(b*T_ + qColB) * D_ + h*64 + dt*16 + 4*quad) = wB;
  }
}

// ---------------- launch ----------------
extern "C" void kernel_launch(void* const* d_in, const int* in_sizes, int n_in,
                              void* d_out, int out_size, void* d_ws, size_t ws_size,
                              hipStream_t stream) {
  const float* x  = (const float*)d_in[0];
  const float* Wq = (const float*)d_in[1];
  const float* Wk = (const float*)d_in[2];
  const float* Wv = (const float*)d_in[3];
  const float* Wp = (const float*)d_in[4];
  const float* qg = (const float*)d_in[5];

  u16* xb   = (u16*)d_ws;                        // 4096 x 1024 (reused as ob)
  u16* wqkv = xb   + (size_t)BT_ * D_;           // 1536 x 1024
  u16* wpb  = wqkv + (size_t)1536 * D_;          // 1024 x 1024 (contiguous after wqkv)
  u16* qkvb = wpb  + (size_t)D_ * D_;            // 4096 x 1280 (Q|K)
  u16* vT   = qkvb + (size_t)BT_ * NQK;          // [2][4][64][2048]
  u16* ob   = xb;

  conv_all_kernel<<<dim3((4194304 + 2621440) / 1024), dim3(256), 0, stream>>>(
      x, Wq, Wk, Wv, Wp, xb);

  gemm_bt<2><<<dim3(24, 32), dim3(128), 0, stream>>>(xb, wqkv, qkvb, vT, qg, BT_, 1536, D_);
  attn_kernel<<<dim3(16, H_, B_), dim3(256), 0, stream>>>(qkvb, vT, ob);
  gemm_bt<0><<<dim3(16, 32), dim3(128), 0, stream>>>(ob, wpb, d_out, (u16*)nullptr, nullptr, BT_, D_, D_);
}

// Round 12
// 159.822 us; speedup vs baseline: 1.1835x; 1.0907x over previous
//
#include <hip/hip_runtime.h>

typedef unsigned short u16;
typedef unsigned int   u32;
typedef __bf16 bfv8 __attribute__((ext_vector_type(8)));   // MFMA A/B frag: 8 bf16
typedef float  f32x4 __attribute__((ext_vector_type(4)));  // MFMA C/D frag
typedef short  s16x4 __attribute__((ext_vector_type(4)));  // 16x16x16 bf16_1k frag

#define B_   2
#define T_   2048
#define D_   1024
#define H_   16
#define HKV_ 4
#define NQK  1280            // qkv buffer holds Q(1024) + K(256); V goes to vT
#define BT_  (B_*T_)
// q_gain fold also includes 1/sqrt(64)=0.125 and log2(e) (softmax in log2 domain)
#define QSCALE 0.18033688011112042f
#define L2_10K 0.41524101186092515f   // log2(10000)/32
#define I2PI   0.15915494309189535f   // 1/(2*pi) — HW trig input is revolutions

__device__ __forceinline__ u16 f2bf(float f) {   // native RNE cvt
  __bf16 h = (__bf16)f; u16 s; __builtin_memcpy(&s, &h, 2); return s;
}

// async global->LDS, 16B per lane; LDS dst = wave-uniform base + lane*16 (m104)
__device__ __forceinline__ void load16(const u16* g, u16* l) {
  auto gp = (const __attribute__((address_space(1))) u32*)(uintptr_t)g;
  auto lp = (__attribute__((address_space(3))) u32*)(uintptr_t)l;
  __builtin_amdgcn_global_load_lds(gp, lp, 16, 0, 0);
}

// HW trig: v_sin_f32/v_cos_f32 take revolutions; explicit fract reduction
__device__ __forceinline__ void hw_sincos_rev(float rev, float& s, float& c) {
  rev -= floorf(rev);                  // folds to v_fract_f32
  s = __builtin_amdgcn_sinf(rev);
  c = __builtin_amdgcn_cosf(rev);
}

// ---------------- fp32 -> bf16 convert: x AND all weights in ONE launch ----------
// dst is contiguous: xb(4194304) | Wq(1048576) | Wk(262144) | Wv(262144) | Wp(1048576)
__global__ void conv_all_kernel(const float* __restrict__ x,
                                const float* __restrict__ wq, const float* __restrict__ wk,
                                const float* __restrict__ wv, const float* __restrict__ wp,
                                u16* __restrict__ dst) {
  int i = (blockIdx.x * 256 + threadIdx.x) * 4;
  const float* s; int off;
  if (i < 4194304) { s = x; off = i; }
  else {
    int j = i - 4194304;
    if      (j < 1048576) { s = wq; off = j; }
    else if (j < 1310720) { s = wk; off = j - 1048576; }
    else if (j < 1572864) { s = wv; off = j - 1310720; }
    else                  { s = wp; off = j - 1572864; }
  }
  float4 v = *(const float4*)(s + off);
  ushort4 o; o.x = f2bf(v.x); o.y = f2bf(v.y); o.z = f2bf(v.z); o.w = f2bf(v.w);
  *(ushort4*)(dst + i) = o;
}

// ---------------- bf16 GEMM, C = A(M,K) @ B(N,K)^T ----------------
// 2-wave blocks (128 thr), tile 128(M) x 64(N), BK=32, DOUBLE-BUFFERED LDS with
// ONE barrier per K-step (attn-proven structure): stage(k+1) issued right
// after the barrier, overlapping compute(k). R10 lesson: the 2-barrier loop
// at ~6 waves/CU is latency-bound (pipe work ~2 us; measured ~40) — the DMA
// latency was fully exposed every iteration.
// MODE 0: f32 out ld=N.
// MODE 2: fused QKV epilogue — block's 64-col range = exactly one head.
//         Q/K heads get RoPE (+q_gain*QSCALE on Q) on fp32 accumulators
//         (HW v_sin/v_cos, NOT libm sincosf — scratch!); V heads scattered
//         transposed to vT[b][kvh][d][t].
template<int MODE>
__global__ __launch_bounds__(128) void gemm_bt(const u16* __restrict__ A,
                                               const u16* __restrict__ Bm,
                                               void* __restrict__ C,
                                               u16* __restrict__ vT,
                                               const float* __restrict__ qg,
                                               int M, int N, int K) {
  __shared__ __align__(16) u16 As[2][128 * 32];   // 16 KB
  __shared__ __align__(16) u16 Bs[2][64 * 32];    //  8 KB
  const int tid  = threadIdx.x;
  const int wave = tid >> 6, lane = tid & 63;
  const int quad = lane >> 4, l16 = lane & 15;
  const int m0 = blockIdx.y * 128, n0 = blockIdx.x * 64;
  const int wm = wave * 64;
  const int lr = lane >> 2, lc = (lane & 3) * 8;   // 4 lanes per 32-half row

  f32x4 acc[4][4];
  for (int mi = 0; mi < 4; ++mi)
    for (int ni = 0; ni < 4; ++ni) acc[mi][ni] = (f32x4){0.f, 0.f, 0.f, 0.f};

  auto stage = [&](int kk, int buf) {
    #pragma unroll
    for (int u = 0; u < 4; ++u) {            // A: 8 chunks of 16 rows
      const int c = u * 2 + wave;            // wave-uniform chunk id
      load16(A + (size_t)(m0 + c*16 + lr) * K + kk + lc, As[buf] + c * 512);
    }
    #pragma unroll
    for (int u = 0; u < 2; ++u) {            // B: 4 chunks of 16 rows
      const int c = u * 2 + wave;
      load16(Bm + (size_t)(n0 + c*16 + lr) * K + kk + lc, Bs[buf] + c * 512);
    }
  };

  const int nIter = K >> 5;                  // 32
  stage(0, 0);
  for (int it = 0; it < nIter; ++it) {
    __syncthreads();                         // implicit vmcnt(0): DMA(it) done;
                                             // also protects buf[(it+1)&1] from prev reads
    if (it + 1 < nIter) stage(((it + 1) << 5), (it + 1) & 1);   // overlaps compute(it)
    const u16* Ab = As[it & 1];
    const u16* Bb = Bs[it & 1];
    bfv8 af[4], bf_[4];
    #pragma unroll
    for (int i = 0; i < 4; ++i) af[i]  = *(const bfv8*)(Ab + (wm + i*16 + l16)*32 + 8*quad);
    #pragma unroll
    for (int i = 0; i < 4; ++i) bf_[i] = *(const bfv8*)(Bb + (i*16 + l16)*32 + 8*quad);
    #pragma unroll
    for (int mi = 0; mi < 4; ++mi)
      #pragma unroll
      for (int ni = 0; ni < 4; ++ni)
        acc[mi][ni] = __builtin_amdgcn_mfma_f32_16x16x32_bf16(af[mi], bf_[ni], acc[mi][ni], 0, 0, 0);
  }

  // C/D layout: row = 4*quad + reg, col = l16 (+16*ni +n0)
  if (MODE == 0) {
    #pragma unroll
    for (int mi = 0; mi < 4; ++mi)
      #pragma unroll
      for (int ni = 0; ni < 4; ++ni)
        #pragma unroll
        for (int r = 0; r < 4; ++r)
          ((float*)C)[(size_t)(m0 + wm + mi*16 + 4*quad + r) * N + n0 + ni*16 + l16]
            = acc[mi][ni][r];
  } else {
    if (n0 < NQK) {                          // Q or K head: apply RoPE here
      const bool isQ = n0 < 1024;
      const float gain = isQ ? qg[n0 >> 6] * QSCALE : 1.0f;
      // lane's head-internal cols: j0=l16 (ni 0/2 pair), j1=l16+16 (ni 1/3 pair)
      const float inv0 = exp2f(-(float)l16 * L2_10K) * I2PI;          // rev/step
      const float inv1 = exp2f(-(float)(l16 + 16) * L2_10K) * I2PI;
      #pragma unroll
      for (int mi = 0; mi < 4; ++mi) {
        const int rowg = m0 + wm + mi*16 + 4*quad;
        u16* dst = (u16*)C + (size_t)rowg * NQK + n0 + l16;
        #pragma unroll
        for (int r = 0; r < 4; ++r) {
          const int t = (rowg + r) & (T_ - 1);
          float s0, c0, s1, c1;
          hw_sincos_rev((float)t * inv0, s0, c0);
          hw_sincos_rev((float)t * inv1, s1, c1);
          const float x1a = acc[mi][0][r], x2a = acc[mi][2][r];
          const float x1b = acc[mi][1][r], x2b = acc[mi][3][r];
          u16* drow = dst + (size_t)r * NQK;
          drow[0]  = f2bf((x1a*c0 - x2a*s0) * gain);
          drow[16] = f2bf((x1b*c1 - x2b*s1) * gain);
          drow[32] = f2bf((x1a*s0 + x2a*c0) * gain);
          drow[48] = f2bf((x1b*s1 + x2b*c1) * gain);
        }
      }
    } else {              // V head -> transposed vT[b][kvh][d][t]
      const int kvh = (n0 - NQK) >> 6;
      #pragma unroll
      for (int mi = 0; mi < 4; ++mi)
        #pragma unroll
        for (int ni = 0; ni < 4; ++ni) {
          const int d = ni*16 + l16;
          const int rowg = m0 + wm + mi*16 + 4*quad;
          const int bb = rowg >> 11, t = rowg & (T_ - 1);
          ushort4 w4;
          w4.x = f2bf(acc[mi][ni][0]); w4.y = f2bf(acc[mi][ni][1]);
          w4.z = f2bf(acc[mi][ni][2]); w4.w = f2bf(acc[mi][ni][3]);
          *(ushort4*)(vT + ((size_t)((bb*HKV_ + kvh)*64 + d)) * T_ + t) = w4;
        }
    }
  }
}

// ---------------- Flash attention (causal, GQA, paired q-tiles, S^T trick) ----------------
// R8 version (best measured: 45.6 us). Paired q-tiles (i, 31-i): uniform 33
// strip-tiles/block AND K/V frag reads shared across both strips (R9 lesson:
// unpairing costs +35% staging & frag reads — pairing is strictly better).
// St = K Q^T (C-layout lane l16 = q-row, keys 4*quad+r) feeds P directly into
// PV (O^T = V^T P^T) as 16x16x16bf16_1k B-frags — no P LDS round-trip.
// Fixed-max softmax (M=0, log2 domain, scores O(1)-bounded).
// COMPILE-TIME strip/diag specialization (R7 lesson: runtime bools get
// if-converted inside unrolled loops -> dead strip's exp2/MFMA chain executes).
template<bool DOA, bool DIAGA, bool DIAGB>
__device__ __forceinline__ void attn_tile(const u16* KB, const u16* VB,
                                          int l16, int quad,
                                          const bfv8* qA, const bfv8* qB,
                                          float& psA, float& psB,
                                          f32x4 oA[4], f32x4 oB[4],
                                          int qColA, int qColB, int s0) {
  const int sw = l16 & 7;
  f32x4 stA[4], stB[4];
  #pragma unroll
  for (int ni = 0; ni < 4; ++ni) {
    const int row = ni*16 + l16;           // key row in K tile
    bfv8 k0 = *(const bfv8*)(KB + row*64 + 8*(quad ^ sw));
    bfv8 k1 = *(const bfv8*)(KB + row*64 + 8*((quad + 4) ^ sw));
    if (DOA) {
      stA[ni] = __builtin_amdgcn_mfma_f32_16x16x32_bf16(k0, qA[0], (f32x4){0.f,0.f,0.f,0.f}, 0, 0, 0);
      stA[ni] = __builtin_amdgcn_mfma_f32_16x16x32_bf16(k1, qA[1], stA[ni], 0, 0, 0);
    }
    stB[ni] = __builtin_amdgcn_mfma_f32_16x16x32_bf16(k0, qB[0], (f32x4){0.f,0.f,0.f,0.f}, 0, 0, 0);
    stB[ni] = __builtin_amdgcn_mfma_f32_16x16x32_bf16(k1, qB[1], stB[ni], 0, 0, 0);
  }
  // mask + exp2 + per-lane row-sum + pack to bf16 B-frags (P^T in registers)
  s16x4 pbA[4], pbB[4];
  #pragma unroll
  for (int ni = 0; ni < 4; ++ni)
    #pragma unroll
    for (int r = 0; r < 4; ++r) {
      const int key = s0 + ni*16 + 4*quad + r;
      if (DOA) {
        float v = stA[ni][r];
        if (DIAGA) v = (key <= qColA) ? v : -3.0e38f;
        const float p = __builtin_amdgcn_exp2f(v);
        psA += p;
        pbA[ni][r] = (short)f2bf(p);
      }
      float v = stB[ni][r];
      if (DIAGB) v = (key <= qColB) ? v : -3.0e38f;
      const float p = __builtin_amdgcn_exp2f(v);
      psB += p;
      pbB[ni][r] = (short)f2bf(p);
    }
  // O^T += V^T P^T  (shared V frags)
  #pragma unroll
  for (int ni = 0; ni < 4; ++ni) {
    const int vofs = 8*((2*ni + (quad >> 1)) ^ sw) + 4*(quad & 1);
    #pragma unroll
    for (int dt = 0; dt < 4; ++dt) {
      s16x4 va = *(const s16x4*)(VB + (dt*16 + l16)*64 + vofs);
      if (DOA) oA[dt] = __builtin_amdgcn_mfma_f32_16x16x16bf16_1k(va, pbA[ni], oA[dt], 0, 0, 0);
      oB[dt] = __builtin_amdgcn_mfma_f32_16x16x16bf16_1k(va, pbB[ni], oB[dt], 0, 0, 0);
    }
  }
}

__global__ __launch_bounds__(256) void attn_kernel(const u16* __restrict__ qkv,
                                                   const u16* __restrict__ vT,
                                                   u16* __restrict__ o) {
  const int pr = blockIdx.x;            // pair id 0..15 -> q-tiles (pr, 31-pr)
  const int h  = blockIdx.y;
  const int b  = blockIdx.z;
  const int kvh = h >> 2;
  const int tid = threadIdx.x;
  const int wave = tid >> 6, lane = tid & 63;
  const int quad = lane >> 4, l16 = lane & 15;

  const int qtA = pr, qtB = 31 - pr;
  const int nk  = qtB + 1;              // qtA < qtB always (pr in 0..15)

  __shared__ __align__(16) u16 Kl[2][64 * 64];
  __shared__ __align__(16) u16 Vl[2][64 * 64];

  const u16* qAp = qkv + (size_t)(b*T_ + qtA*64 + wave*16 + l16) * NQK + h*64 + 8*quad;
  const u16* qBp = qkv + (size_t)(b*T_ + qtB*64 + wave*16 + l16) * NQK + h*64 + 8*quad;
  const bfv8 qA[2] = { *(const bfv8*)qAp, *(const bfv8*)(qAp + 32) };
  const bfv8 qB[2] = { *(const bfv8*)qBp, *(const bfv8*)(qBp + 32) };

  float psA = 0.f, psB = 0.f;
  f32x4 oA[4], oB[4];
  #pragma unroll
  for (int d = 0; d < 4; ++d) oA[d] = oB[d] = (f32x4){0.f, 0.f, 0.f, 0.f};

  const int srow = lane >> 3, slot = lane & 7;
  const u16* Kg = qkv + (size_t)(b*T_) * NQK + 1024 + kvh*64;
  const u16* Vg = vT  + (size_t)((b*HKV_ + kvh) * 64) * T_;

  auto stage = [&](int kt, int buf) {
    const int s0 = kt * 64;
    #pragma unroll
    for (int u = 0; u < 2; ++u) {
      const int base = wave*16 + u*8;
      const int r  = base + srow;
      const int kc = slot ^ (r & 7);           // XOR chunk swizzle
      load16(Kg + (size_t)(s0 + r) * NQK + kc*8, Kl[buf] + base*64);
      load16(Vg + (size_t)r * T_ + s0 + kc*8,    Vl[buf] + base*64);
    }
  };

  stage(0, 0);
  const int qColA = qtA*64 + wave*16 + l16;    // lane's q row (strip A)
  const int qColB = qtB*64 + wave*16 + l16;

  // Phase 1: kt in [0, qtA) — both strips, no diag
  for (int kt = 0; kt < qtA; ++kt) {
    __syncthreads();
    stage(kt + 1, (kt + 1) & 1);
    attn_tile<true, false, false>(Kl[kt & 1], Vl[kt & 1], l16, quad, qA, qB,
                                  psA, psB, oA, oB, qColA, qColB, kt*64);
  }
  // kt = qtA — both strips, diag on A (qtA < nk-1 always)
  {
    const int kt = qtA;
    __syncthreads();
    stage(kt + 1, (kt + 1) & 1);
    attn_tile<true, true, false>(Kl[kt & 1], Vl[kt & 1], l16, quad, qA, qB,
                                 psA, psB, oA, oB, qColA, qColB, kt*64);
  }
  // Phase 2: kt in (qtA, nk-1) — strip B only
  for (int kt = qtA + 1; kt < nk - 1; ++kt) {
    __syncthreads();
    stage(kt + 1, (kt + 1) & 1);
    attn_tile<false, false, false>(Kl[kt & 1], Vl[kt & 1], l16, quad, qA, qB,
                                   psA, psB, oA, oB, qColA, qColB, kt*64);
  }
  // kt = nk-1 — strip B, diag
  {
    const int kt = nk - 1;
    __syncthreads();
    attn_tile<false, false, true>(Kl[kt & 1], Vl[kt & 1], l16, quad, qA, qB,
                                  psA, psB, oA, oB, qColA, qColB, kt*64);
  }

  // row sums: partials live on the 4 quads of each q-row lane
  #pragma unroll
  for (int off = 16; off < 64; off <<= 1) {
    psA += __shfl_xor(psA, off);
    psB += __shfl_xor(psB, off);
  }
  const float ivA = 1.0f / psA, ivB = 1.0f / psB;

  // O^T C-layout: col=l16=qrow, row=4*quad+r = d (+16*dt) -> pack 4 d's per store
  #pragma unroll
  for (int dt = 0; dt < 4; ++dt) {
    ushort4 wA, wB;
    wA.x = f2bf(oA[dt][0]*ivA); wA.y = f2bf(oA[dt][1]*ivA);
    wA.z = f2bf(oA[dt][2]*ivA); wA.w = f2bf(oA[dt][3]*ivA);
    wB.x = f2bf(oB[dt][0]*ivB); wB.y = f2bf(oB[dt][1]*ivB);
    wB.z = f2bf(oB[dt][2]*ivB); wB.w = f2bf(oB[dt][3]*ivB);
    *(ushort4*)(o + (size_t)(b*T_ + qColA) * D_ + h*64 + dt*16 + 4*quad) = wA;
    *(ushort4*)(o + (size_t)(b*T_ + qColB) * D_ + h*64 + dt*16 + 4*quad) = wB;
  }
}

// ---------------- launch ----------------
extern "C" void kernel_launch(void* const* d_in, const int* in_sizes, int n_in,
                              void* d_out, int out_size, void* d_ws, size_t ws_size,
                              hipStream_t stream) {
  const float* x  = (const float*)d_in[0];
  const float* Wq = (const float*)d_in[1];
  const float* Wk = (const float*)d_in[2];
  const float* Wv = (const float*)d_in[3];
  const float* Wp = (const float*)d_in[4];
  const float* qg = (const float*)d_in[5];

  u16* xb   = (u16*)d_ws;                        // 4096 x 1024 (reused as ob)
  u16* wqkv = xb   + (size_t)BT_ * D_;           // 1536 x 1024
  u16* wpb  = wqkv + (size_t)1536 * D_;          // 1024 x 1024 (contiguous after wqkv)
  u16* qkvb = wpb  + (size_t)D_ * D_;            // 4096 x 1280 (Q|K)
  u16* vT   = qkvb + (size_t)BT_ * NQK;          // [2][4][64][2048]
  u16* ob   = xb;

  conv_all_kernel<<<dim3((4194304 + 2621440) / 1024), dim3(256), 0, stream>>>(
      x, Wq, Wk, Wv, Wp, xb);

  gemm_bt<2><<<dim3(24, 32), dim3(128), 0, stream>>>(xb, wqkv, qkvb, vT, qg, BT_, 1536, D_);
  attn_kernel<<<dim3(16, H_, B_), dim3(256), 0, stream>>>(qkvb, vT, ob);
  gemm_bt<0><<<dim3(16, 32), dim3(128), 0, stream>>>(ob, wpb, d_out, (u16*)nullptr, nullptr, BT_, D_, D_);
}